// Round 16
// baseline (845.497 us; speedup 1.0000x reference)
//
#include <hip/hip_runtime.h>

// ---------------------------------------------------------------------------
// Routed top-2 MoE for MI355X (gfx950).  Round 16:
//  gemm1 split: k_gate (acts@wr2h K=128, r9-verified 128x128 single-buffer)
//  writes silu(gate) bf16 into hbuf; k_gemm1 becomes a pure x@w3 256x256
//  8-phase GEMM (r14-gemm2-validated body: T=16, vmcnt(4) @ p4/p8) whose
//  epilogue reads the gate from hbuf, multiplies, overwrites in place.
//  16 MFMA per fenced phase (was 8) + half the B-traffic per FLOP.
//  gemm2 / route / transposes identical to r15 (best known, 783 us).
// ---------------------------------------------------------------------------

#define DEV static __device__ __forceinline__

typedef float  f32x4  __attribute__((ext_vector_type(4)));
typedef __bf16 bf16x8 __attribute__((ext_vector_type(8)));

#define VMCNT_(n) asm volatile("s_waitcnt vmcnt(" #n ")" ::: "memory")
#define VMCNT(n) VMCNT_(n)

DEV unsigned short f2bf(float f) {
  union { float f; unsigned u; } v; v.f = f;
  unsigned r = v.u + 0x7fffu + ((v.u >> 16) & 1u);   // RNE
  return (unsigned short)(r >> 16);
}
DEV float bf2f(unsigned short b) {
  union { unsigned u; float f; } v; v.u = ((unsigned)b) << 16;
  return v.f;
}

DEV void gll16(const void* g, void* l) {
  __builtin_amdgcn_global_load_lds(
      (const __attribute__((address_space(1))) unsigned int*)g,
      (__attribute__((address_space(3))) unsigned int*)l, 16, 0, 0);
}

DEV f32x4 mfma16(bf16x8 a, bf16x8 b, f32x4 c) {
  return __builtin_amdgcn_mfma_f32_16x16x32_bf16(a, b, c, 0, 0, 0);
}

// Bijective XCD chunk swizzle (m204 general form).
DEV int xcd_swz_gen(int bid, int nwg) {
  int x = bid & 7, o = bid >> 3;
  int q = nwg >> 3, r = nwg & 7;
  return (x < r ? x * (q + 1) : r * (q + 1) + (x - r) * q) + o;
}

// ---- BK=64 tile layout (verified r1-r15: 0 bank conflicts) ----------------
DEV bf16x8 frag_read(const unsigned short* lds, int row, int kb) {
  int off = row * 128 + ((kb * 2) ^ ((row & 7) << 4));
  return *(const bf16x8*)((const char*)lds + off);
}
DEV void stage_linear(const unsigned short* base, size_t pitch, int k0,
                      unsigned short* lds, int tid) {
  int wq = tid >> 6, lane = tid & 63;
#pragma unroll
  for (int i = 0; i < 4; ++i) {
    int s = wq * 256 + i * 64 + lane;
    int row = s >> 3, b = s & 7;
    int bb = b ^ (row & 7);
    const unsigned short* g = base + (size_t)row * pitch + (size_t)(k0 + bb * 8);
    gll16(g, lds + (size_t)(wq * 256 + i * 64) * 8);
  }
}
DEV void stage_gather(const unsigned short* base, size_t pitch, size_t colOff,
                      int k0, const int* toks, unsigned short* lds, int tid) {
  int wq = tid >> 6, lane = tid & 63;
#pragma unroll
  for (int i = 0; i < 4; ++i) {
    int s = wq * 256 + i * 64 + lane;
    int row = s >> 3, b = s & 7;
    int bb = b ^ (row & 7);
    const unsigned short* g =
        base + (size_t)toks[row] * pitch + colOff + (size_t)(k0 + bb * 8);
    gll16(g, lds + (size_t)(wq * 256 + i * 64) * 8);
  }
}
// 4 waves (2Mx2N), per-wave 64x64, acc 4x4; one BK=64 step = 16 MFMA/wave.
DEV void mfma_block(const unsigned short* A, const unsigned short* B,
                    f32x4 (&acc)[4][4], int wm, int wn, int lg, int lc) {
#pragma unroll
  for (int ks = 0; ks < 2; ++ks) {
    int kb = ks * 32 + lg * 8;
    bf16x8 af[4], bff[4];
#pragma unroll
    for (int i = 0; i < 4; ++i) {
      af[i]  = frag_read(A, wm * 64 + i * 16 + lc, kb);
      bff[i] = frag_read(B, wn * 64 + i * 16 + lc, kb);
    }
#pragma unroll
    for (int mf = 0; mf < 4; ++mf)
#pragma unroll
      for (int nf = 0; nf < 4; ++nf)
        acc[mf][nf] = mfma16(af[mf], bff[nf], acc[mf][nf]);
  }
}

// ---------------------------------------------------------------------------

__global__ __launch_bounds__(256) void k_cast_x(const float* __restrict__ x,
    unsigned short* __restrict__ xh, unsigned short* __restrict__ xl) {
  int stride = gridDim.x * blockDim.x;
  for (int i = blockIdx.x * blockDim.x + threadIdx.x; i < 8192 * 1024 / 4;
       i += stride) {
    float4 v = ((const float4*)x)[i];
    ushort4 h, l;
    h.x = f2bf(v.x); l.x = f2bf(v.x - bf2f(h.x));
    h.y = f2bf(v.y); l.y = f2bf(v.y - bf2f(h.y));
    h.z = f2bf(v.z); l.z = f2bf(v.z - bf2f(h.z));
    h.w = f2bf(v.w); l.w = f2bf(v.w - bf2f(h.w));
    ((ushort4*)xh)[i] = h;
    ((ushort4*)xl)[i] = l;
  }
}

__global__ void k_zero(int* cnt, float* probsum) {
  int t = threadIdx.x;
  if (t < 16) cnt[t] = 0;
  if (t < 8)  probsum[t] = 0.f;
}

// Transpose fp32 [E][K][N] -> bf16 [E][N][K] via 64x64 LDS tiles.
__global__ __launch_bounds__(256) void k_transp(const float* __restrict__ src,
    unsigned short* __restrict__ dst, int K, int N) {
  int ntn = N >> 6;
  int kt = blockIdx.x / ntn, nt = blockIdx.x % ntn;
  int e = blockIdx.y;
  __shared__ float tl[64][65];
  const float* s = src + (size_t)e * K * N;
  unsigned short* d = dst + (size_t)e * N * K;
  int tid = threadIdx.x;
  int c4 = (tid & 15) * 4, rr = tid >> 4;
#pragma unroll
  for (int p = 0; p < 4; ++p) {
    int row = rr + p * 16;
    float4 v = *(const float4*)(s + (size_t)(kt * 64 + row) * N + nt * 64 + c4);
    tl[row][c4] = v.x; tl[row][c4 + 1] = v.y;
    tl[row][c4 + 2] = v.z; tl[row][c4 + 3] = v.w;
  }
  __syncthreads();
#pragma unroll
  for (int p = 0; p < 4; ++p) {
    int n = rr + p * 16;
    ushort4 o;
    o.x = f2bf(tl[c4 + 0][n]); o.y = f2bf(tl[c4 + 1][n]);
    o.z = f2bf(tl[c4 + 2][n]); o.w = f2bf(tl[c4 + 3][n]);
    *(ushort4*)(d + (size_t)(nt * 64 + n) * K + kt * 64 + c4) = o;
  }
}

// Same transpose but emits hi/lo bf16 split (for w_route).
__global__ __launch_bounds__(256) void k_transp_split(const float* __restrict__ src,
    unsigned short* __restrict__ dh, unsigned short* __restrict__ dl, int K, int N) {
  int ntn = N >> 6;
  int kt = blockIdx.x / ntn, nt = blockIdx.x % ntn;
  int e = blockIdx.y;
  __shared__ float tl[64][65];
  const float* s = src + (size_t)e * K * N;
  size_t dbase = (size_t)e * N * K;
  int tid = threadIdx.x;
  int c4 = (tid & 15) * 4, rr = tid >> 4;
#pragma unroll
  for (int p = 0; p < 4; ++p) {
    int row = rr + p * 16;
    float4 v = *(const float4*)(s + (size_t)(kt * 64 + row) * N + nt * 64 + c4);
    tl[row][c4] = v.x; tl[row][c4 + 1] = v.y;
    tl[row][c4 + 2] = v.z; tl[row][c4 + 3] = v.w;
  }
  __syncthreads();
#pragma unroll
  for (int p = 0; p < 4; ++p) {
    int n = rr + p * 16;
    ushort4 oh, ol;
#pragma unroll
    for (int i = 0; i < 4; ++i) {
      float v = tl[c4 + i][n];
      unsigned short hh = f2bf(v);
      unsigned short ll = f2bf(v - bf2f(hh));
      ((unsigned short*)&oh)[i] = hh;
      ((unsigned short*)&ol)[i] = ll;
    }
    *(ushort4*)(dh + dbase + (size_t)(nt * 64 + n) * K + kt * 64 + c4) = oh;
    *(ushort4*)(dl + dbase + (size_t)(nt * 64 + n) * K + kt * 64 + c4) = ol;
  }
}

// Routing GEMM: acts[n, e*128+r] = x . w_route, 3-term bf16 split; fp32 norms.
__global__ __launch_bounds__(256) void k_route_gemm(
    const unsigned short* __restrict__ xh, const unsigned short* __restrict__ xl,
    const unsigned short* __restrict__ wrh_t, const unsigned short* __restrict__ wrl_t,
    unsigned short* __restrict__ acts, float* __restrict__ norms_out) {
  __shared__ __align__(16) unsigned short Ah[128 * 64], Al[128 * 64];
  __shared__ __align__(16) unsigned short Bh[128 * 64], Bl[128 * 64];
  __shared__ float ssq_s[128][2];
  int tid = threadIdx.x;
  int mt = blockIdx.x, e = blockIdx.y;
  int wq = tid >> 6, lane = tid & 63;
  int wm = wq >> 1, wn = wq & 1, lg = lane >> 4, lc = lane & 15;
  f32x4 acc[4][4] = {};
  const unsigned short* ah_src = xh + (size_t)mt * 128 * 1024;
  const unsigned short* al_src = xl + (size_t)mt * 128 * 1024;
  const unsigned short* bh_src = wrh_t + (size_t)e * 128 * 1024;
  const unsigned short* bl_src = wrl_t + (size_t)e * 128 * 1024;
  for (int kt = 0; kt < 16; ++kt) {
    int k0 = kt * 64;
    stage_linear(ah_src, 1024, k0, Ah, tid);
    stage_linear(al_src, 1024, k0, Al, tid);
    stage_linear(bh_src, 1024, k0, Bh, tid);
    stage_linear(bl_src, 1024, k0, Bl, tid);
    __syncthreads();
#pragma unroll
    for (int ks = 0; ks < 2; ++ks) {
      int kb = ks * 32 + lg * 8;
      bf16x8 ahf[4], alf[4], bhf[4], blf[4];
#pragma unroll
      for (int i = 0; i < 4; ++i) {
        ahf[i] = frag_read(Ah, wm * 64 + i * 16 + lc, kb);
        alf[i] = frag_read(Al, wm * 64 + i * 16 + lc, kb);
        bhf[i] = frag_read(Bh, wn * 64 + i * 16 + lc, kb);
        blf[i] = frag_read(Bl, wn * 64 + i * 16 + lc, kb);
      }
#pragma unroll
      for (int mf = 0; mf < 4; ++mf)
#pragma unroll
        for (int nf = 0; nf < 4; ++nf) {
          acc[mf][nf] = mfma16(ahf[mf], bhf[nf], acc[mf][nf]);
          acc[mf][nf] = mfma16(alf[mf], bhf[nf], acc[mf][nf]);
          acc[mf][nf] = mfma16(ahf[mf], blf[nf], acc[mf][nf]);
        }
    }
    __syncthreads();
  }
  float ssq[4][4];
#pragma unroll
  for (int mf = 0; mf < 4; ++mf)
#pragma unroll
    for (int r = 0; r < 4; ++r) ssq[mf][r] = 0.f;
#pragma unroll
  for (int mf = 0; mf < 4; ++mf)
#pragma unroll
    for (int nf = 0; nf < 4; ++nf)
#pragma unroll
      for (int r = 0; r < 4; ++r) {
        float v = acc[mf][nf][r];
        int row = wm * 64 + mf * 16 + lg * 4 + r;
        int col = wn * 64 + nf * 16 + lc;
        acts[(size_t)(mt * 128 + row) * 1024 + e * 128 + col] = f2bf(v);
        ssq[mf][r] += v * v;
      }
#pragma unroll
  for (int mf = 0; mf < 4; ++mf)
#pragma unroll
    for (int r = 0; r < 4; ++r) {
      float s = ssq[mf][r];
      s += __shfl_xor(s, 1); s += __shfl_xor(s, 2);
      s += __shfl_xor(s, 4); s += __shfl_xor(s, 8);
      if (lc == 0) ssq_s[wm * 64 + mf * 16 + lg * 4 + r][wn] = s;
    }
  __syncthreads();
  if (tid < 128) {
    float s = ssq_s[tid][0] + ssq_s[tid][1];
    norms_out[(size_t)(mt * 128 + tid) * 8 + e] = sqrtf(s);
  }
}

// Per-token softmax + top-2.
__global__ __launch_bounds__(256) void k_router(const float* __restrict__ norms,
    float* __restrict__ topw, int* __restrict__ sel,
    int* __restrict__ cnt, float* __restrict__ probsum) {
  __shared__ float ps_s[8];
  __shared__ int cnt_s[16];
  int tid = threadIdx.x;
  if (tid < 8)  ps_s[tid] = 0.f;
  if (tid < 16) cnt_s[tid] = 0;
  __syncthreads();
  int n = blockIdx.x * 256 + tid;
  float p[8], mx = -3.4e38f;
#pragma unroll
  for (int e = 0; e < 8; ++e) { p[e] = norms[(size_t)n * 8 + e]; mx = fmaxf(mx, p[e]); }
  float s = 0.f;
#pragma unroll
  for (int e = 0; e < 8; ++e) { p[e] = __expf(p[e] - mx); s += p[e]; }
  float inv = 1.f / s;
  int i1 = 0; float v1 = p[0];
#pragma unroll
  for (int e = 1; e < 8; ++e) if (p[e] > v1) { v1 = p[e]; i1 = e; }
  int i2 = -1; float v2 = -1.f;
#pragma unroll
  for (int e = 0; e < 8; ++e) if (e != i1 && p[e] > v2) { v2 = p[e]; i2 = e; }
  float wsum = v1 + v2;
  topw[n * 2 + 0] = v1 / wsum;
  topw[n * 2 + 1] = v2 / wsum;
  sel[n * 2 + 0] = i1;
  sel[n * 2 + 1] = i2;
  atomicAdd(&cnt_s[i1], 1);
  atomicAdd(&cnt_s[8 + i2], 1);
#pragma unroll
  for (int e = 0; e < 8; ++e) atomicAdd(&ps_s[e], p[e] * inv);
  __syncthreads();
  if (tid < 8)  atomicAdd(&probsum[tid], ps_s[tid]);
  if (tid < 16) atomicAdd(&cnt[tid], cnt_s[tid]);
}

// Planner: 256-row map (<=80), bl_loss.
__global__ void k_plan(const int* __restrict__ cnt, const float* __restrict__ probsum,
                       int* __restrict__ offs, int* __restrict__ fill,
                       int4* __restrict__ tilemap, float* __restrict__ bl_out) {
  int4* map256 = tilemap;
  int t = 0;
  for (int k = 0; k < 2; ++k) {
    int pos = 0;
    for (int e = 0; e < 8; ++e) {
      int c = cnt[k * 8 + e];
      offs[k * 8 + e] = pos;
      int ntl = (c + 255) >> 8;
      for (int i = 0; i < ntl; ++i) {
        int rr = c - i * 256; if (rr > 256) rr = 256;
        map256[t] = make_int4(e, k * 8192 + pos + i * 256, rr, 0);
        ++t;
      }
      pos += c;
    }
  }
  for (; t < 80; ++t) map256[t] = make_int4(0, 0, 0, 0);
  for (int i = 0; i < 16; ++i) fill[i] = 0;
  float bl = 0.f;
  for (int e = 0; e < 8; ++e)
    bl += ((float)(cnt[e] + cnt[8 + e]) / 8192.f) * (probsum[e] / 8192.f);
  *bl_out = bl * 8.f;
}

__global__ __launch_bounds__(256) void k_fill(const int* __restrict__ sel,
    const float* __restrict__ topw, const int* __restrict__ offs,
    int* __restrict__ fill, int* __restrict__ list01, float* __restrict__ wlist) {
  int n = blockIdx.x * 256 + threadIdx.x;
#pragma unroll
  for (int k = 0; k < 2; ++k) {
    int e = sel[n * 2 + k];
    int pos = atomicAdd(&fill[k * 8 + e], 1);
    int idx = k * 8192 + offs[k * 8 + e] + pos;
    list01[idx] = n;
    wlist[idx] = topw[n * 2 + k];
  }
}

// ---------------------------------------------------------------------------
// GATE: hbuf[slot, hcol] = silu(acts[tok, e*128:]+ @ wr2h[e][:, hcol]).
// 128 rows x 128 h-cols per block, K=128 (2 BK-steps), single-buffered
// (r9-verified loop).  Grid: nt128 * 32.
// ---------------------------------------------------------------------------
__global__ __launch_bounds__(256) void k_gate(
    const unsigned short* __restrict__ acts, const unsigned short* __restrict__ wr2h_t,
    const int* __restrict__ list, const int4* __restrict__ map256, int tile_lo256,
    int nt128, unsigned short* __restrict__ hbuf) {
  __shared__ __align__(16) unsigned short A[128 * 64], B[128 * 64];
  __shared__ int toks[128];
  int wg = xcd_swz_gen((int)blockIdx.x, nt128 * 32);
  int t128 = wg >> 5, bn = wg & 31;
  int4 ent = map256[tile_lo256 + (t128 >> 1)];
  int h = t128 & 1;
  int e = ent.x;
  int posbase = ent.y + h * 128;
  int rows = ent.z - h * 128;
  if (rows <= 0) return;
  if (rows > 128) rows = 128;
  int tid = threadIdx.x;
  if (tid < 128) {
    int rr = tid < rows ? tid : rows - 1;
    toks[tid] = list[posbase + rr];
  }
  __syncthreads();
  int wq = tid >> 6, lane = tid & 63;
  int wm = wq >> 1, wn = wq & 1, lg = lane >> 4, lc = lane & 15;
  f32x4 acc[4][4] = {};
  const unsigned short* bsrc = wr2h_t + ((size_t)e * 4096 + bn * 128) * 128;
  for (int kt = 0; kt < 2; ++kt) {
    int k0 = kt * 64;
    stage_gather(acts, 1024, (size_t)e * 128, k0, toks, A, tid);
    stage_linear(bsrc, 128, k0, B, tid);
    __syncthreads();
    mfma_block(A, B, acc, wm, wn, lg, lc);
    __syncthreads();
  }
  size_t hrow0 = (size_t)t128 * 128;
#pragma unroll
  for (int mf = 0; mf < 4; ++mf)
#pragma unroll
    for (int nf = 0; nf < 4; ++nf)
#pragma unroll
      for (int r = 0; r < 4; ++r) {
        int row = wm * 64 + mf * 16 + lg * 4 + r;
        if (row < rows) {
          int col = wn * 64 + nf * 16 + lc;
          float sv = acc[mf][nf][r];
          float g = sv / (1.f + __expf(-sv));
          hbuf[(hrow0 + row) * 4096 + (size_t)bn * 128 + col] = f2bf(g);
        }
      }
}

// ---------------------------------------------------------------------------
// GEMM1: pure x@w3, 256 tokens x 256 h-cols, 8-phase (r14-gemm2-validated
// body: T=16 K-tiles, 7 steady iterations + final pair, vmcnt(4) @ p4/p8).
// Epilogue: h = acc * gate (gate read from hbuf, overwritten in place).
// ---------------------------------------------------------------------------
__global__ __launch_bounds__(512, 2) void k_gemm1(
    const unsigned short* __restrict__ xh, const unsigned short* __restrict__ w3t,
    const int* __restrict__ list, const int4* __restrict__ map256, int tile_lo,
    int nt, unsigned short* __restrict__ hbuf) {
  __shared__ __align__(16) unsigned short SA[2][256 * 64];
  __shared__ __align__(16) unsigned short SB[2][256 * 64];
  __shared__ int toks[256];
  int wg = xcd_swz_gen((int)blockIdx.x, nt * 16);
  int tloc = wg >> 4, bn = wg & 15;
  int4 ent = map256[tile_lo + tloc];
  int e = ent.x, posbase = ent.y, rows = ent.z;
  if (rows == 0) return;
  int tid = threadIdx.x;
  if (tid < 256) {
    int rr = tid < rows ? tid : rows - 1;
    toks[tid] = list[posbase + rr];
  }
  __syncthreads();
  int wq = tid >> 6, lane = tid & 63;
  int wm = wq >> 2, wn = wq & 3, lg = lane >> 4, lc = lane & 15;

  int s0 = tid, s1 = tid + 512;
  int r0 = s0 >> 3, c0 = ((s0 & 7) ^ (r0 & 7)) * 8;
  int r1 = s1 >> 3, c1 = ((s1 & 7) ^ (r1 & 7)) * 8;
  const unsigned short* a00 = xh + (size_t)toks[r0] * 1024 + c0;
  const unsigned short* a01 = xh + (size_t)toks[r1] * 1024 + c1;
  const unsigned short* a10 = xh + (size_t)toks[128 + r0] * 1024 + c0;
  const unsigned short* a11 = xh + (size_t)toks[128 + r1] * 1024 + c1;
  const unsigned short* b0 = w3t + ((size_t)e * 4096 + bn * 256 + r0) * 1024 + c0;
  const unsigned short* b1 = w3t + ((size_t)e * 4096 + bn * 256 + r1) * 1024 + c1;

  auto stA = [&](int kt, int h, int bi) {
    const unsigned short* p0 = h ? a10 : a00;
    const unsigned short* p1 = h ? a11 : a01;
    gll16(p0 + kt * 64, &SA[bi][(size_t)(h * 1024 + s0) * 8]);
    gll16(p1 + kt * 64, &SA[bi][(size_t)(h * 1024 + s1) * 8]);
  };
  auto stB = [&](int kt, int h, int bi) {
    size_t ho = (size_t)h * 128 * 1024;
    gll16(b0 + ho + kt * 64, &SB[bi][(size_t)(h * 1024 + s0) * 8]);
    gll16(b1 + ho + kt * 64, &SB[bi][(size_t)(h * 1024 + s1) * 8]);
  };

  f32x4 acc[2][4][2][2] = {};
  bf16x8 af[4][2], bf[2][2][2];

#define RA(BI, QM)                                                           \
  _Pragma("unroll") for (int mf = 0; mf < 4; ++mf)                           \
  _Pragma("unroll") for (int k2 = 0; k2 < 2; ++k2)                           \
    af[mf][k2] = frag_read(SA[BI], wm * 128 + QM * 64 + mf * 16 + lc,        \
                           k2 * 32 + lg * 8);
#define RB(BI, QN)                                                           \
  _Pragma("unroll") for (int nf = 0; nf < 2; ++nf)                           \
  _Pragma("unroll") for (int k2 = 0; k2 < 2; ++k2)                           \
    bf[QN][nf][k2] = frag_read(SB[BI], wn * 64 + QN * 32 + nf * 16 + lc,     \
                               k2 * 32 + lg * 8);
#define PH_MMA(QM, QN)                                                       \
  __builtin_amdgcn_sched_barrier(0);                                         \
  __builtin_amdgcn_s_barrier();                                              \
  asm volatile("s_waitcnt lgkmcnt(0)" ::: "memory");                         \
  __builtin_amdgcn_sched_barrier(0);                                         \
  __builtin_amdgcn_s_setprio(1);                                             \
  _Pragma("unroll") for (int mf = 0; mf < 4; ++mf)                           \
  _Pragma("unroll") for (int nf = 0; nf < 2; ++nf)                           \
  _Pragma("unroll") for (int k2 = 0; k2 < 2; ++k2)                           \
    acc[QM][mf][QN][nf] =                                                    \
        mfma16(af[mf][k2], bf[QN][nf][k2], acc[QM][mf][QN][nf]);             \
  __builtin_amdgcn_s_setprio(0);                                             \
  __builtin_amdgcn_sched_barrier(0);                                         \
  __builtin_amdgcn_s_barrier();

  stA(0, 0, 0); stA(0, 1, 0); stB(0, 0, 0); stB(0, 1, 0);
  stB(1, 0, 1); stB(1, 1, 1);
  VMCNT(4);
  __builtin_amdgcn_s_barrier();

  for (int it = 0; it < 7; ++it) {
    int u = 2 * it;
    RA(0, 0); RB(0, 0); stA(u + 1, 0, 1);
    PH_MMA(0, 0);
    RB(0, 1); stA(u + 1, 1, 1);
    PH_MMA(0, 1);
    RA(0, 1); stB(u + 2, 0, 0);
    PH_MMA(1, 1);
    stB(u + 2, 1, 0);
    VMCNT(4);
    PH_MMA(1, 0);
    RA(1, 0); RB(1, 0); stA(u + 2, 0, 0);
    PH_MMA(0, 0);
    RB(1, 1); stA(u + 2, 1, 0);
    PH_MMA(0, 1);
    RA(1, 1); stB(u + 3, 0, 1);
    PH_MMA(1, 1);
    stB(u + 3, 1, 1);
    VMCNT(4);
    PH_MMA(1, 0);
  }
  // final pair: tiles 14 (buf0), 15 (buf1).
  {
    RA(0, 0); RB(0, 0); stA(15, 0, 1);
    PH_MMA(0, 0);
    RB(0, 1); stA(15, 1, 1);
    PH_MMA(0, 1);
    RA(0, 1);
    PH_MMA(1, 1);
    VMCNT(0);
    PH_MMA(1, 0);
    RA(1, 0); RB(1, 0);
    PH_MMA(0, 0);
    RB(1, 1);
    PH_MMA(0, 1);
    RA(1, 1);
    PH_MMA(1, 1);
    PH_MMA(1, 0);
  }
#undef RA
#undef RB
#undef PH_MMA

  size_t hrow0 = (size_t)tloc * 256;
#pragma unroll
  for (int qm = 0; qm < 2; ++qm)
#pragma unroll
    for (int mf = 0; mf < 4; ++mf)
#pragma unroll
      for (int qn = 0; qn < 2; ++qn)
#pragma unroll
        for (int nf = 0; nf < 2; ++nf)
#pragma unroll
          for (int r = 0; r < 4; ++r) {
            int row = wm * 128 + qm * 64 + mf * 16 + lg * 4 + r;
            if (row < rows) {
              int col = wn * 64 + qn * 32 + nf * 16 + lc;
              size_t idx = (hrow0 + row) * 4096 + (size_t)bn * 256 + col;
              float g = bf2f(hbuf[idx]);
              hbuf[idx] = f2bf(acc[qm][mf][qn][nf][r] * g);
            }
          }
}

// ---------------------------------------------------------------------------
// GEMM2 (r12/r15-validated): 8-phase, 256x256, K-split x2 (K-half 2048,
// T=32), vmcnt(4) @ p4/p8; bn-innermost decode.
// ---------------------------------------------------------------------------
__global__ __launch_bounds__(512, 2) void k_gemm2(
    const unsigned short* __restrict__ hbuf, const unsigned short* __restrict__ wh2dt,
    const int* __restrict__ list, const float* __restrict__ wlist,
    const int4* __restrict__ map256, int tile_lo, int nt,
    float* __restrict__ out) {
  __shared__ __align__(16) unsigned short SA[2][256 * 64];
  __shared__ __align__(16) unsigned short SB[2][256 * 64];
  __shared__ int toks[256];
  __shared__ float wr_s[256];
  int wg = xcd_swz_gen((int)blockIdx.x, nt * 8);
  int tloc = wg >> 3, bn = wg & 3, ks = (wg >> 2) & 1;
  int4 ent = map256[tile_lo + tloc];
  int e = ent.x, posbase = ent.y, rows = ent.z;
  if (rows == 0) return;
  int tid = threadIdx.x;
  if (tid < 256) {
    int rr = tid < rows ? tid : rows - 1;
    toks[tid] = list[posbase + rr];
    wr_s[tid] = wlist[posbase + rr];
  }
  __syncthreads();
  int wq = tid >> 6, lane = tid & 63;
  int wm = wq >> 2, wn = wq & 3, lg = lane >> 4, lc = lane & 15;
  int kbase = ks * 2048;

  int s0 = tid, s1 = tid + 512;
  int r0 = s0 >> 3, c0 = ((s0 & 7) ^ (r0 & 7)) * 8;
  int r1 = s1 >> 3, c1 = ((s1 & 7) ^ (r1 & 7)) * 8;
  const unsigned short* a0 = hbuf + ((size_t)tloc * 256 + r0) * 4096 + kbase + c0;
  const unsigned short* a1 = hbuf + ((size_t)tloc * 256 + r1) * 4096 + kbase + c1;
  const unsigned short* b0 =
      wh2dt + ((size_t)e * 1024 + bn * 256 + r0) * 4096 + kbase + c0;
  const unsigned short* b1 =
      wh2dt + ((size_t)e * 1024 + bn * 256 + r1) * 4096 + kbase + c1;

  auto stA = [&](int kt, int h, int bi) {
    size_t ho = (size_t)h * 128 * 4096;
    gll16(a0 + ho + kt * 64, &SA[bi][(size_t)(h * 1024 + s0) * 8]);
    gll16(a1 + ho + kt * 64, &SA[bi][(size_t)(h * 1024 + s1) * 8]);
  };
  auto stB = [&](int kt, int h, int bi) {
    size_t ho = (size_t)h * 128 * 4096;
    gll16(b0 + ho + kt * 64, &SB[bi][(size_t)(h * 1024 + s0) * 8]);
    gll16(b1 + ho + kt * 64, &SB[bi][(size_t)(h * 1024 + s1) * 8]);
  };

  f32x4 acc[2][4][2][2] = {};
  bf16x8 af[4][2], bf[2][2][2];

#define RA(BI, QM)                                                           \
  _Pragma("unroll") for (int mf = 0; mf < 4; ++mf)                           \
  _Pragma("unroll") for (int k2 = 0; k2 < 2; ++k2)                           \
    af[mf][k2] = frag_read(SA[BI], wm * 128 + QM * 64 + mf * 16 + lc,        \
                           k2 * 32 + lg * 8);
#define RB(BI, QN)                                                           \
  _Pragma("unroll") for (int nf = 0; nf < 2; ++nf)                           \
  _Pragma("unroll") for (int k2 = 0; k2 < 2; ++k2)                           \
    bf[QN][nf][k2] = frag_read(SB[BI], wn * 64 + QN * 32 + nf * 16 + lc,     \
                               k2 * 32 + lg * 8);
#define PH_MMA(QM, QN)                                                       \
  __builtin_amdgcn_sched_barrier(0);                                         \
  __builtin_amdgcn_s_barrier();                                              \
  asm volatile("s_waitcnt lgkmcnt(0)" ::: "memory");                         \
  __builtin_amdgcn_sched_barrier(0);                                         \
  __builtin_amdgcn_s_setprio(1);                                             \
  _Pragma("unroll") for (int mf = 0; mf < 4; ++mf)                           \
  _Pragma("unroll") for (int nf = 0; nf < 2; ++nf)                           \
  _Pragma("unroll") for (int k2 = 0; k2 < 2; ++k2)                           \
    acc[QM][mf][QN][nf] =                                                    \
        mfma16(af[mf][k2], bf[QN][nf][k2], acc[QM][mf][QN][nf]);             \
  __builtin_amdgcn_s_setprio(0);                                             \
  __builtin_amdgcn_sched_barrier(0);                                         \
  __builtin_amdgcn_s_barrier();

  stA(0, 0, 0); stA(0, 1, 0); stB(0, 0, 0); stB(0, 1, 0);
  stB(1, 0, 1); stB(1, 1, 1);
  VMCNT(4);
  __builtin_amdgcn_s_barrier();

  for (int it = 0; it < 15; ++it) {
    int u = 2 * it;
    RA(0, 0); RB(0, 0); stA(u + 1, 0, 1);
    PH_MMA(0, 0);
    RB(0, 1); stA(u + 1, 1, 1);
    PH_MMA(0, 1);
    RA(0, 1); stB(u + 2, 0, 0);
    PH_MMA(1, 1);
    stB(u + 2, 1, 0);
    VMCNT(4);
    PH_MMA(1, 0);
    RA(1, 0); RB(1, 0); stA(u + 2, 0, 0);
    PH_MMA(0, 0);
    RB(1, 1); stA(u + 2, 1, 0);
    PH_MMA(0, 1);
    RA(1, 1); stB(u + 3, 0, 1);
    PH_MMA(1, 1);
    stB(u + 3, 1, 1);
    VMCNT(4);
    PH_MMA(1, 0);
  }
  {
    RA(0, 0); RB(0, 0); stA(31, 0, 1);
    PH_MMA(0, 0);
    RB(0, 1); stA(31, 1, 1);
    PH_MMA(0, 1);
    RA(0, 1);
    PH_MMA(1, 1);
    VMCNT(0);
    PH_MMA(1, 0);
    RA(1, 0); RB(1, 0);
    PH_MMA(0, 0);
    RB(1, 1);
    PH_MMA(0, 1);
    RA(1, 1);
    PH_MMA(1, 1);
    PH_MMA(1, 0);
  }
#undef RA
#undef RB
#undef PH_MMA

#pragma unroll
  for (int qm = 0; qm < 2; ++qm)
#pragma unroll
    for (int mf = 0; mf < 4; ++mf)
#pragma unroll
      for (int qn = 0; qn < 2; ++qn)
#pragma unroll
        for (int nf = 0; nf < 2; ++nf)
#pragma unroll
          for (int r = 0; r < 4; ++r) {
            int row = wm * 128 + qm * 64 + mf * 16 + lg * 4 + r;
            if (row < rows) {
              int col = wn * 64 + qn * 32 + nf * 16 + lc;
              float v = acc[qm][mf][qn][nf][r] * wr_s[row];
              atomicAdd(out + (size_t)toks[row] * 1024 + bn * 256 + col, v);
            }
          }
}

// ---------------------------------------------------------------------------

extern "C" void kernel_launch(void* const* d_in, const int* in_sizes, int n_in,
                              void* d_out, int out_size, void* d_ws, size_t ws_size,
                              hipStream_t stream) {
  (void)in_sizes; (void)n_in; (void)out_size;
  const float* x      = (const float*)d_in[0];
  const float* wroute = (const float*)d_in[1];
  const float* w3     = (const float*)d_in[2];
  const float* wr2h   = (const float*)d_in[3];
  const float* wh2d   = (const float*)d_in[4];
  float* out = (float*)d_out;

  char* ws = (char*)d_ws;
  size_t off = 0;
  auto carve = [&](size_t bytes) -> void* {
    void* p = ws + off; off += (bytes + 255) & ~(size_t)255; return p;
  };
  unsigned short* xh     = (unsigned short*)carve((size_t)8192 * 1024 * 2);
  unsigned short* xl     = (unsigned short*)carve((size_t)8192 * 1024 * 2);
  unsigned short* wrh_t  = (unsigned short*)carve((size_t)8 * 128 * 1024 * 2);
  unsigned short* wrl_t  = (unsigned short*)carve((size_t)8 * 128 * 1024 * 2);
  unsigned short* w3t    = (unsigned short*)carve((size_t)8 * 4096 * 1024 * 2);
  unsigned short* wr2h_t = (unsigned short*)carve((size_t)8 * 4096 * 128 * 2);
  unsigned short* wh2dt  = (unsigned short*)carve((size_t)8 * 1024 * 4096 * 2);
  unsigned short* acts   = (unsigned short*)carve((size_t)8192 * 1024 * 2);
  int*   list01 = (int*)carve(2 * 8192 * 4);
  float* wlist  = (float*)carve(2 * 8192 * 4);
  int*   sel    = (int*)carve(8192 * 2 * 4);
  float* topw   = (float*)carve(8192 * 2 * 4);
  int*   ctr    = (int*)carve(8192);
  int* cnt = ctr; int* fill = ctr + 16; int* offs = ctr + 32;
  float* probsum = (float*)(ctr + 48);
  int4* tilemap = (int4*)(ctr + 64);    // 80 x map256

  size_t avail = ws_size > off ? ws_size - off : 0;
  int tpc = 0;
  const int cands[4] = {160, 80, 40, 20};   // in 128-row units (even)
  for (int i = 0; i < 4; ++i) {
    if ((size_t)cands[i] * 128 * 4096 * 2 <= avail) { tpc = cands[i]; break; }
  }
  if (!tpc) return;
  unsigned short* hbuf = (unsigned short*)(ws + off);

  float* norms_out = out + 8388608;   // [N, E] fp32
  float* bl_out    = out + 8454144;   // scalar

  hipMemsetAsync(out, 0, (size_t)8388608 * 4, stream);
  k_cast_x<<<2048, 256, 0, stream>>>(x, xh, xl);
  k_zero<<<1, 64, 0, stream>>>(cnt, probsum);
  k_transp<<<dim3(16 * 64, 8), 256, 0, stream>>>(w3, w3t, 1024, 4096);
  k_transp<<<dim3(64 * 16, 8), 256, 0, stream>>>(wh2d, wh2dt, 4096, 1024);
  k_transp<<<dim3(2 * 64, 8), 256, 0, stream>>>(wr2h, wr2h_t, 128, 4096);
  k_transp_split<<<dim3(16 * 2, 8), 256, 0, stream>>>(wroute, wrh_t, wrl_t, 1024, 128);
  k_route_gemm<<<dim3(64, 8), 256, 0, stream>>>(xh, xl, wrh_t, wrl_t, acts, norms_out);
  k_router<<<32, 256, 0, stream>>>(norms_out, topw, sel, cnt, probsum);
  k_plan<<<1, 1, 0, stream>>>(cnt, probsum, offs, fill, tilemap, bl_out);
  k_fill<<<32, 256, 0, stream>>>(sel, topw, offs, fill, list01, wlist);

  int nchunk = (160 + tpc - 1) / tpc;
  for (int c = 0; c < nchunk; ++c) {
    int tile_lo = c * tpc;              // 128-row units
    int nt = 160 - tile_lo < tpc ? 160 - tile_lo : tpc;
    k_gate<<<nt * 32, 256, 0, stream>>>(
        acts, wr2h_t, list01, tilemap, tile_lo / 2, nt, hbuf);
    k_gemm1<<<(nt / 2) * 16, 512, 0, stream>>>(
        xh, w3t, list01, tilemap, tile_lo / 2, nt / 2, hbuf);
    k_gemm2<<<(nt / 2) * 8, 512, 0, stream>>>(
        hbuf, wh2dt, list01, wlist, tilemap, tile_lo / 2, nt / 2, out);
  }
}

// Round 17
// 783.227 us; speedup vs baseline: 1.0795x; 1.0795x over previous
//
#include <hip/hip_runtime.h>

// ---------------------------------------------------------------------------
// Routed top-2 MoE for MI355X (gfx950).  Round 17 = final: revert to r15,
// the measured best configuration (783 us, absmax 0.03125):
//  - gemm1: r12-validated 8-phase 256x128, dual acc (main + silu gate),
//    vmcnt(2) @ p4/p8, fenced phases.
//  - gemm2: r12-validated 8-phase 256x256, K-split x2, vmcnt(4) @ p4/p8,
//    bn-innermost decode.
//  r16's gate-split (256-wide gemm1) was neutral on the GEMM and added
//  ~60 us of gate-kernel overhead; reverted.
// ---------------------------------------------------------------------------

#define DEV static __device__ __forceinline__

typedef float  f32x4  __attribute__((ext_vector_type(4)));
typedef __bf16 bf16x8 __attribute__((ext_vector_type(8)));

#define VMCNT_(n) asm volatile("s_waitcnt vmcnt(" #n ")" ::: "memory")
#define VMCNT(n) VMCNT_(n)

DEV unsigned short f2bf(float f) {
  union { float f; unsigned u; } v; v.f = f;
  unsigned r = v.u + 0x7fffu + ((v.u >> 16) & 1u);   // RNE
  return (unsigned short)(r >> 16);
}
DEV float bf2f(unsigned short b) {
  union { unsigned u; float f; } v; v.u = ((unsigned)b) << 16;
  return v.f;
}

DEV void gll16(const void* g, void* l) {
  __builtin_amdgcn_global_load_lds(
      (const __attribute__((address_space(1))) unsigned int*)g,
      (__attribute__((address_space(3))) unsigned int*)l, 16, 0, 0);
}

DEV f32x4 mfma16(bf16x8 a, bf16x8 b, f32x4 c) {
  return __builtin_amdgcn_mfma_f32_16x16x32_bf16(a, b, c, 0, 0, 0);
}

// Bijective XCD chunk swizzle (m204 general form).
DEV int xcd_swz_gen(int bid, int nwg) {
  int x = bid & 7, o = bid >> 3;
  int q = nwg >> 3, r = nwg & 7;
  return (x < r ? x * (q + 1) : r * (q + 1) + (x - r) * q) + o;
}

// ---- BK=64 tile layout (verified r1-r15: 0 bank conflicts) ----------------
DEV bf16x8 frag_read(const unsigned short* lds, int row, int kb) {
  int off = row * 128 + ((kb * 2) ^ ((row & 7) << 4));
  return *(const bf16x8*)((const char*)lds + off);
}
DEV void stage_linear(const unsigned short* base, size_t pitch, int k0,
                      unsigned short* lds, int tid) {
  int wq = tid >> 6, lane = tid & 63;
#pragma unroll
  for (int i = 0; i < 4; ++i) {
    int s = wq * 256 + i * 64 + lane;
    int row = s >> 3, b = s & 7;
    int bb = b ^ (row & 7);
    const unsigned short* g = base + (size_t)row * pitch + (size_t)(k0 + bb * 8);
    gll16(g, lds + (size_t)(wq * 256 + i * 64) * 8);
  }
}

// ---------------------------------------------------------------------------

__global__ __launch_bounds__(256) void k_cast_x(const float* __restrict__ x,
    unsigned short* __restrict__ xh, unsigned short* __restrict__ xl) {
  int stride = gridDim.x * blockDim.x;
  for (int i = blockIdx.x * blockDim.x + threadIdx.x; i < 8192 * 1024 / 4;
       i += stride) {
    float4 v = ((const float4*)x)[i];
    ushort4 h, l;
    h.x = f2bf(v.x); l.x = f2bf(v.x - bf2f(h.x));
    h.y = f2bf(v.y); l.y = f2bf(v.y - bf2f(h.y));
    h.z = f2bf(v.z); l.z = f2bf(v.z - bf2f(h.z));
    h.w = f2bf(v.w); l.w = f2bf(v.w - bf2f(h.w));
    ((ushort4*)xh)[i] = h;
    ((ushort4*)xl)[i] = l;
  }
}

__global__ void k_zero(int* cnt, float* probsum) {
  int t = threadIdx.x;
  if (t < 16) cnt[t] = 0;
  if (t < 8)  probsum[t] = 0.f;
}

// Transpose fp32 [E][K][N] -> bf16 [E][N][K] via 64x64 LDS tiles.
__global__ __launch_bounds__(256) void k_transp(const float* __restrict__ src,
    unsigned short* __restrict__ dst, int K, int N) {
  int ntn = N >> 6;
  int kt = blockIdx.x / ntn, nt = blockIdx.x % ntn;
  int e = blockIdx.y;
  __shared__ float tl[64][65];
  const float* s = src + (size_t)e * K * N;
  unsigned short* d = dst + (size_t)e * N * K;
  int tid = threadIdx.x;
  int c4 = (tid & 15) * 4, rr = tid >> 4;
#pragma unroll
  for (int p = 0; p < 4; ++p) {
    int row = rr + p * 16;
    float4 v = *(const float4*)(s + (size_t)(kt * 64 + row) * N + nt * 64 + c4);
    tl[row][c4] = v.x; tl[row][c4 + 1] = v.y;
    tl[row][c4 + 2] = v.z; tl[row][c4 + 3] = v.w;
  }
  __syncthreads();
#pragma unroll
  for (int p = 0; p < 4; ++p) {
    int n = rr + p * 16;
    ushort4 o;
    o.x = f2bf(tl[c4 + 0][n]); o.y = f2bf(tl[c4 + 1][n]);
    o.z = f2bf(tl[c4 + 2][n]); o.w = f2bf(tl[c4 + 3][n]);
    *(ushort4*)(d + (size_t)(nt * 64 + n) * K + kt * 64 + c4) = o;
  }
}

// Same transpose but emits hi/lo bf16 split (for w_route).
__global__ __launch_bounds__(256) void k_transp_split(const float* __restrict__ src,
    unsigned short* __restrict__ dh, unsigned short* __restrict__ dl, int K, int N) {
  int ntn = N >> 6;
  int kt = blockIdx.x / ntn, nt = blockIdx.x % ntn;
  int e = blockIdx.y;
  __shared__ float tl[64][65];
  const float* s = src + (size_t)e * K * N;
  size_t dbase = (size_t)e * N * K;
  int tid = threadIdx.x;
  int c4 = (tid & 15) * 4, rr = tid >> 4;
#pragma unroll
  for (int p = 0; p < 4; ++p) {
    int row = rr + p * 16;
    float4 v = *(const float4*)(s + (size_t)(kt * 64 + row) * N + nt * 64 + c4);
    tl[row][c4] = v.x; tl[row][c4 + 1] = v.y;
    tl[row][c4 + 2] = v.z; tl[row][c4 + 3] = v.w;
  }
  __syncthreads();
#pragma unroll
  for (int p = 0; p < 4; ++p) {
    int n = rr + p * 16;
    ushort4 oh, ol;
#pragma unroll
    for (int i = 0; i < 4; ++i) {
      float v = tl[c4 + i][n];
      unsigned short hh = f2bf(v);
      unsigned short ll = f2bf(v - bf2f(hh));
      ((unsigned short*)&oh)[i] = hh;
      ((unsigned short*)&ol)[i] = ll;
    }
    *(ushort4*)(dh + dbase + (size_t)(nt * 64 + n) * K + kt * 64 + c4) = oh;
    *(ushort4*)(dl + dbase + (size_t)(nt * 64 + n) * K + kt * 64 + c4) = ol;
  }
}

// Routing GEMM: acts[n, e*128+r] = x . w_route, 3-term bf16 split; fp32 norms.
__global__ __launch_bounds__(256) void k_route_gemm(
    const unsigned short* __restrict__ xh, const unsigned short* __restrict__ xl,
    const unsigned short* __restrict__ wrh_t, const unsigned short* __restrict__ wrl_t,
    unsigned short* __restrict__ acts, float* __restrict__ norms_out) {
  __shared__ __align__(16) unsigned short Ah[128 * 64], Al[128 * 64];
  __shared__ __align__(16) unsigned short Bh[128 * 64], Bl[128 * 64];
  __shared__ float ssq_s[128][2];
  int tid = threadIdx.x;
  int mt = blockIdx.x, e = blockIdx.y;
  int wq = tid >> 6, lane = tid & 63;
  int wm = wq >> 1, wn = wq & 1, lg = lane >> 4, lc = lane & 15;
  f32x4 acc[4][4] = {};
  const unsigned short* ah_src = xh + (size_t)mt * 128 * 1024;
  const unsigned short* al_src = xl + (size_t)mt * 128 * 1024;
  const unsigned short* bh_src = wrh_t + (size_t)e * 128 * 1024;
  const unsigned short* bl_src = wrl_t + (size_t)e * 128 * 1024;
  for (int kt = 0; kt < 16; ++kt) {
    int k0 = kt * 64;
    stage_linear(ah_src, 1024, k0, Ah, tid);
    stage_linear(al_src, 1024, k0, Al, tid);
    stage_linear(bh_src, 1024, k0, Bh, tid);
    stage_linear(bl_src, 1024, k0, Bl, tid);
    __syncthreads();
#pragma unroll
    for (int ks = 0; ks < 2; ++ks) {
      int kb = ks * 32 + lg * 8;
      bf16x8 ahf[4], alf[4], bhf[4], blf[4];
#pragma unroll
      for (int i = 0; i < 4; ++i) {
        ahf[i] = frag_read(Ah, wm * 64 + i * 16 + lc, kb);
        alf[i] = frag_read(Al, wm * 64 + i * 16 + lc, kb);
        bhf[i] = frag_read(Bh, wn * 64 + i * 16 + lc, kb);
        blf[i] = frag_read(Bl, wn * 64 + i * 16 + lc, kb);
      }
#pragma unroll
      for (int mf = 0; mf < 4; ++mf)
#pragma unroll
        for (int nf = 0; nf < 4; ++nf) {
          acc[mf][nf] = mfma16(ahf[mf], bhf[nf], acc[mf][nf]);
          acc[mf][nf] = mfma16(alf[mf], bhf[nf], acc[mf][nf]);
          acc[mf][nf] = mfma16(ahf[mf], blf[nf], acc[mf][nf]);
        }
    }
    __syncthreads();
  }
  float ssq[4][4];
#pragma unroll
  for (int mf = 0; mf < 4; ++mf)
#pragma unroll
    for (int r = 0; r < 4; ++r) ssq[mf][r] = 0.f;
#pragma unroll
  for (int mf = 0; mf < 4; ++mf)
#pragma unroll
    for (int nf = 0; nf < 4; ++nf)
#pragma unroll
      for (int r = 0; r < 4; ++r) {
        float v = acc[mf][nf][r];
        int row = wm * 64 + mf * 16 + lg * 4 + r;
        int col = wn * 64 + nf * 16 + lc;
        acts[(size_t)(mt * 128 + row) * 1024 + e * 128 + col] = f2bf(v);
        ssq[mf][r] += v * v;
      }
#pragma unroll
  for (int mf = 0; mf < 4; ++mf)
#pragma unroll
    for (int r = 0; r < 4; ++r) {
      float s = ssq[mf][r];
      s += __shfl_xor(s, 1); s += __shfl_xor(s, 2);
      s += __shfl_xor(s, 4); s += __shfl_xor(s, 8);
      if (lc == 0) ssq_s[wm * 64 + mf * 16 + lg * 4 + r][wn] = s;
    }
  __syncthreads();
  if (tid < 128) {
    float s = ssq_s[tid][0] + ssq_s[tid][1];
    norms_out[(size_t)(mt * 128 + tid) * 8 + e] = sqrtf(s);
  }
}

// Per-token softmax + top-2.
__global__ __launch_bounds__(256) void k_router(const float* __restrict__ norms,
    float* __restrict__ topw, int* __restrict__ sel,
    int* __restrict__ cnt, float* __restrict__ probsum) {
  __shared__ float ps_s[8];
  __shared__ int cnt_s[16];
  int tid = threadIdx.x;
  if (tid < 8)  ps_s[tid] = 0.f;
  if (tid < 16) cnt_s[tid] = 0;
  __syncthreads();
  int n = blockIdx.x * 256 + tid;
  float p[8], mx = -3.4e38f;
#pragma unroll
  for (int e = 0; e < 8; ++e) { p[e] = norms[(size_t)n * 8 + e]; mx = fmaxf(mx, p[e]); }
  float s = 0.f;
#pragma unroll
  for (int e = 0; e < 8; ++e) { p[e] = __expf(p[e] - mx); s += p[e]; }
  float inv = 1.f / s;
  int i1 = 0; float v1 = p[0];
#pragma unroll
  for (int e = 1; e < 8; ++e) if (p[e] > v1) { v1 = p[e]; i1 = e; }
  int i2 = -1; float v2 = -1.f;
#pragma unroll
  for (int e = 0; e < 8; ++e) if (e != i1 && p[e] > v2) { v2 = p[e]; i2 = e; }
  float wsum = v1 + v2;
  topw[n * 2 + 0] = v1 / wsum;
  topw[n * 2 + 1] = v2 / wsum;
  sel[n * 2 + 0] = i1;
  sel[n * 2 + 1] = i2;
  atomicAdd(&cnt_s[i1], 1);
  atomicAdd(&cnt_s[8 + i2], 1);
#pragma unroll
  for (int e = 0; e < 8; ++e) atomicAdd(&ps_s[e], p[e] * inv);
  __syncthreads();
  if (tid < 8)  atomicAdd(&probsum[tid], ps_s[tid]);
  if (tid < 16) atomicAdd(&cnt[tid], cnt_s[tid]);
}

// Planner: 256-row map (<=80), bl_loss.
__global__ void k_plan(const int* __restrict__ cnt, const float* __restrict__ probsum,
                       int* __restrict__ offs, int* __restrict__ fill,
                       int4* __restrict__ tilemap, float* __restrict__ bl_out) {
  int4* map256 = tilemap;
  int t = 0;
  for (int k = 0; k < 2; ++k) {
    int pos = 0;
    for (int e = 0; e < 8; ++e) {
      int c = cnt[k * 8 + e];
      offs[k * 8 + e] = pos;
      int ntl = (c + 255) >> 8;
      for (int i = 0; i < ntl; ++i) {
        int rr = c - i * 256; if (rr > 256) rr = 256;
        map256[t] = make_int4(e, k * 8192 + pos + i * 256, rr, 0);
        ++t;
      }
      pos += c;
    }
  }
  for (; t < 80; ++t) map256[t] = make_int4(0, 0, 0, 0);
  for (int i = 0; i < 16; ++i) fill[i] = 0;
  float bl = 0.f;
  for (int e = 0; e < 8; ++e)
    bl += ((float)(cnt[e] + cnt[8 + e]) / 8192.f) * (probsum[e] / 8192.f);
  *bl_out = bl * 8.f;
}

__global__ __launch_bounds__(256) void k_fill(const int* __restrict__ sel,
    const float* __restrict__ topw, const int* __restrict__ offs,
    int* __restrict__ fill, int* __restrict__ list01, float* __restrict__ wlist) {
  int n = blockIdx.x * 256 + threadIdx.x;
#pragma unroll
  for (int k = 0; k < 2; ++k) {
    int e = sel[n * 2 + k];
    int pos = atomicAdd(&fill[k * 8 + e], 1);
    int idx = k * 8192 + offs[k * 8 + e] + pos;
    list01[idx] = n;
    wlist[idx] = topw[n * 2 + k];
  }
}

// ---------------------------------------------------------------------------
// GEMM1 (r12-validated): 8-phase.  256 tokens x 128 h-cols (bn in [0,32)),
// BK=64, T = 16 main + 2 gate K-tiles, dual acc, 8 waves 2Mx4N,
// dbuf LDS 96 KB, vmcnt(2) @ p4/p8, fenced phases.
// ---------------------------------------------------------------------------
__global__ __launch_bounds__(512, 2) void k_gemm1(
    const unsigned short* __restrict__ xh, const unsigned short* __restrict__ acts,
    const unsigned short* __restrict__ w3t, const unsigned short* __restrict__ wr2h_t,
    const int* __restrict__ list, const int4* __restrict__ map256, int tile_lo,
    int nt, unsigned short* __restrict__ hbuf) {
  __shared__ __align__(16) unsigned short SA[2][256 * 64];
  __shared__ __align__(16) unsigned short SB[2][128 * 64];
  __shared__ int toks[256];
  int wg = xcd_swz_gen((int)blockIdx.x, nt * 32);
  int tloc = wg >> 5, bn = wg & 31;
  int4 ent = map256[tile_lo + tloc];
  int e = ent.x, posbase = ent.y, rows = ent.z;
  if (rows == 0) return;
  int tid = threadIdx.x;
  if (tid < 256) {
    int rr = tid < rows ? tid : rows - 1;
    toks[tid] = list[posbase + rr];
  }
  __syncthreads();
  int wq = tid >> 6, lane = tid & 63;
  int wm = wq >> 2, wn = wq & 3, lg = lane >> 4, lc = lane & 15;

  int s0 = tid, s1 = tid + 512;
  int r0 = s0 >> 3, c0 = ((s0 & 7) ^ (r0 & 7)) * 8;
  int r1 = s1 >> 3, c1 = ((s1 & 7) ^ (r1 & 7)) * 8;
  const unsigned short* a00 = xh + (size_t)toks[r0] * 1024 + c0;
  const unsigned short* a01 = xh + (size_t)toks[r1] * 1024 + c1;
  const unsigned short* a10 = xh + (size_t)toks[128 + r0] * 1024 + c0;
  const unsigned short* a11 = xh + (size_t)toks[128 + r1] * 1024 + c1;
  ptrdiff_t dA = (acts - xh) + e * 128;
  int rb = tid >> 3, cb = ((tid & 7) ^ (rb & 7)) * 8;
  const unsigned short* b0 = w3t + ((size_t)e * 4096 + bn * 128 + rb) * 1024 + cb;
  const unsigned short* b1 = w3t + ((size_t)e * 4096 + bn * 128 + 64 + rb) * 1024 + cb;
  const unsigned short* q0 = wr2h_t + ((size_t)e * 4096 + bn * 128 + rb) * 128 + cb;
  const unsigned short* q1 = wr2h_t + ((size_t)e * 4096 + bn * 128 + 64 + rb) * 128 + cb;

  auto stA = [&](int kt, int h, int bi) {
    unsigned short* d0 = &SA[bi][(size_t)(h * 1024 + s0) * 8];
    unsigned short* d1 = &SA[bi][(size_t)(h * 1024 + s1) * 8];
    const unsigned short* p0 = h ? a10 : a00;
    const unsigned short* p1 = h ? a11 : a01;
    if (kt < 16) { gll16(p0 + kt * 64, d0); gll16(p1 + kt * 64, d1); }
    else {
      gll16(p0 + dA + (kt - 16) * 64, d0);
      gll16(p1 + dA + (kt - 16) * 64, d1);
    }
  };
  auto stB = [&](int kt, int h, int bi) {
    unsigned short* d = &SB[bi][(size_t)(h * 512 + tid) * 8];
    if (kt < 16) gll16((h ? b1 : b0) + kt * 64, d);
    else         gll16((h ? q1 : q0) + (kt - 16) * 64, d);
  };

  f32x4 acc_a[2][4][2] = {}, acc_g[2][4][2] = {};
  bf16x8 af[4][2], bf[2][2];

#define RA1(BI, QM)                                                          \
  _Pragma("unroll") for (int mf = 0; mf < 4; ++mf)                           \
  _Pragma("unroll") for (int k2 = 0; k2 < 2; ++k2)                           \
    af[mf][k2] = frag_read(SA[BI], wm * 128 + QM * 64 + mf * 16 + lc,        \
                           k2 * 32 + lg * 8);
#define RB1(BI, QN)                                                          \
  _Pragma("unroll") for (int k2 = 0; k2 < 2; ++k2)                           \
    bf[QN][k2] = frag_read(SB[BI], wn * 32 + QN * 16 + lc, k2 * 32 + lg * 8);
#define PH1(ACC, QM, QN)                                                     \
  __builtin_amdgcn_sched_barrier(0);                                         \
  __builtin_amdgcn_s_barrier();                                              \
  asm volatile("s_waitcnt lgkmcnt(0)" ::: "memory");                         \
  __builtin_amdgcn_sched_barrier(0);                                         \
  __builtin_amdgcn_s_setprio(1);                                             \
  _Pragma("unroll") for (int mf = 0; mf < 4; ++mf)                           \
  _Pragma("unroll") for (int k2 = 0; k2 < 2; ++k2)                           \
    ACC[QM][mf][QN] = mfma16(af[mf][k2], bf[QN][k2], ACC[QM][mf][QN]);       \
  __builtin_amdgcn_s_setprio(0);                                             \
  __builtin_amdgcn_sched_barrier(0);                                         \
  __builtin_amdgcn_s_barrier();

  stA(0, 0, 0); stA(0, 1, 0); stB(0, 0, 0); stB(0, 1, 0);
  stB(1, 0, 1); stB(1, 1, 1);
  VMCNT(2);
  __builtin_amdgcn_s_barrier();

  for (int it = 0; it < 8; ++it) {
    int u = 2 * it;
    RA1(0, 0); RB1(0, 0); stA(u + 1, 0, 1);
    PH1(acc_a, 0, 0);
    RB1(0, 1); stA(u + 1, 1, 1);
    PH1(acc_a, 0, 1);
    RA1(0, 1); stB(u + 2, 0, 0);
    PH1(acc_a, 1, 1);
    stB(u + 2, 1, 0);
    VMCNT(2);
    PH1(acc_a, 1, 0);
    RA1(1, 0); RB1(1, 0); stA(u + 2, 0, 0);
    PH1(acc_a, 0, 0);
    RB1(1, 1); stA(u + 2, 1, 0);
    PH1(acc_a, 0, 1);
    RA1(1, 1); stB(u + 3, 0, 1);
    PH1(acc_a, 1, 1);
    stB(u + 3, 1, 1);
    VMCNT(2);
    PH1(acc_a, 1, 0);
  }
  {
    RA1(0, 0); RB1(0, 0); stA(17, 0, 1);
    PH1(acc_g, 0, 0);
    RB1(0, 1); stA(17, 1, 1);
    PH1(acc_g, 0, 1);
    RA1(0, 1);
    PH1(acc_g, 1, 1);
    VMCNT(0);
    PH1(acc_g, 1, 0);
    RA1(1, 0); RB1(1, 0);
    PH1(acc_g, 0, 0);
    RB1(1, 1);
    PH1(acc_g, 0, 1);
    RA1(1, 1);
    PH1(acc_g, 1, 1);
    PH1(acc_g, 1, 0);
  }
#undef RA1
#undef RB1
#undef PH1

  size_t hrow0 = (size_t)tloc * 256;
#pragma unroll
  for (int qm = 0; qm < 2; ++qm)
#pragma unroll
    for (int mf = 0; mf < 4; ++mf)
#pragma unroll
      for (int qn = 0; qn < 2; ++qn)
#pragma unroll
        for (int r = 0; r < 4; ++r) {
          int row = wm * 128 + qm * 64 + mf * 16 + lg * 4 + r;
          if (row < rows) {
            int col = wn * 32 + qn * 16 + lc;
            float sv = acc_g[qm][mf][qn][r];
            float hv = acc_a[qm][mf][qn][r] * (sv / (1.f + __expf(-sv)));
            hbuf[(hrow0 + row) * 4096 + (size_t)bn * 128 + col] = f2bf(hv);
          }
        }
}

// ---------------------------------------------------------------------------
// GEMM2 (r12-validated): 8-phase, 256x256, K-split x2 (K-half 2048, T=32),
// vmcnt(4) @ p4/p8; bn-innermost decode for A-panel L2 sharing.
// ---------------------------------------------------------------------------
__global__ __launch_bounds__(512, 2) void k_gemm2(
    const unsigned short* __restrict__ hbuf, const unsigned short* __restrict__ wh2dt,
    const int* __restrict__ list, const float* __restrict__ wlist,
    const int4* __restrict__ map256, int tile_lo, int nt,
    float* __restrict__ out) {
  __shared__ __align__(16) unsigned short SA[2][256 * 64];
  __shared__ __align__(16) unsigned short SB[2][256 * 64];
  __shared__ int toks[256];
  __shared__ float wr_s[256];
  int wg = xcd_swz_gen((int)blockIdx.x, nt * 8);
  int tloc = wg >> 3, bn = wg & 3, ks = (wg >> 2) & 1;
  int4 ent = map256[tile_lo + tloc];
  int e = ent.x, posbase = ent.y, rows = ent.z;
  if (rows == 0) return;
  int tid = threadIdx.x;
  if (tid < 256) {
    int rr = tid < rows ? tid : rows - 1;
    toks[tid] = list[posbase + rr];
    wr_s[tid] = wlist[posbase + rr];
  }
  __syncthreads();
  int wq = tid >> 6, lane = tid & 63;
  int wm = wq >> 2, wn = wq & 3, lg = lane >> 4, lc = lane & 15;
  int kbase = ks * 2048;

  int s0 = tid, s1 = tid + 512;
  int r0 = s0 >> 3, c0 = ((s0 & 7) ^ (r0 & 7)) * 8;
  int r1 = s1 >> 3, c1 = ((s1 & 7) ^ (r1 & 7)) * 8;
  const unsigned short* a0 = hbuf + ((size_t)tloc * 256 + r0) * 4096 + kbase + c0;
  const unsigned short* a1 = hbuf + ((size_t)tloc * 256 + r1) * 4096 + kbase + c1;
  const unsigned short* b0 =
      wh2dt + ((size_t)e * 1024 + bn * 256 + r0) * 4096 + kbase + c0;
  const unsigned short* b1 =
      wh2dt + ((size_t)e * 1024 + bn * 256 + r1) * 4096 + kbase + c1;

  auto stA = [&](int kt, int h, int bi) {
    size_t ho = (size_t)h * 128 * 4096;
    gll16(a0 + ho + kt * 64, &SA[bi][(size_t)(h * 1024 + s0) * 8]);
    gll16(a1 + ho + kt * 64, &SA[bi][(size_t)(h * 1024 + s1) * 8]);
  };
  auto stB = [&](int kt, int h, int bi) {
    size_t ho = (size_t)h * 128 * 4096;
    gll16(b0 + ho + kt * 64, &SB[bi][(size_t)(h * 1024 + s0) * 8]);
    gll16(b1 + ho + kt * 64, &SB[bi][(size_t)(h * 1024 + s1) * 8]);
  };

  f32x4 acc[2][4][2][2] = {};
  bf16x8 af[4][2], bf[2][2][2];

#define RA(BI, QM)                                                           \
  _Pragma("unroll") for (int mf = 0; mf < 4; ++mf)                           \
  _Pragma("unroll") for (int k2 = 0; k2 < 2; ++k2)                           \
    af[mf][k2] = frag_read(SA[BI], wm * 128 + QM * 64 + mf * 16 + lc,        \
                           k2 * 32 + lg * 8);
#define RB(BI, QN)                                                           \
  _Pragma("unroll") for (int nf = 0; nf < 2; ++nf)                           \
  _Pragma("unroll") for (int k2 = 0; k2 < 2; ++k2)                           \
    bf[QN][nf][k2] = frag_read(SB[BI], wn * 64 + QN * 32 + nf * 16 + lc,     \
                               k2 * 32 + lg * 8);
#define PH_MMA(QM, QN)                                                       \
  __builtin_amdgcn_sched_barrier(0);                                         \
  __builtin_amdgcn_s_barrier();                                              \
  asm volatile("s_waitcnt lgkmcnt(0)" ::: "memory");                         \
  __builtin_amdgcn_sched_barrier(0);                                         \
  __builtin_amdgcn_s_setprio(1);                                             \
  _Pragma("unroll") for (int mf = 0; mf < 4; ++mf)                           \
  _Pragma("unroll") for (int nf = 0; nf < 2; ++nf)                           \
  _Pragma("unroll") for (int k2 = 0; k2 < 2; ++k2)                           \
    acc[QM][mf][QN][nf] =                                                    \
        mfma16(af[mf][k2], bf[QN][nf][k2], acc[QM][mf][QN][nf]);             \
  __builtin_amdgcn_s_setprio(0);                                             \
  __builtin_amdgcn_sched_barrier(0);                                         \
  __builtin_amdgcn_s_barrier();

  stA(0, 0, 0); stA(0, 1, 0); stB(0, 0, 0); stB(0, 1, 0);
  stB(1, 0, 1); stB(1, 1, 1);
  VMCNT(4);
  __builtin_amdgcn_s_barrier();

  for (int it = 0; it < 15; ++it) {
    int u = 2 * it;
    RA(0, 0); RB(0, 0); stA(u + 1, 0, 1);
    PH_MMA(0, 0);
    RB(0, 1); stA(u + 1, 1, 1);
    PH_MMA(0, 1);
    RA(0, 1); stB(u + 2, 0, 0);
    PH_MMA(1, 1);
    stB(u + 2, 1, 0);
    VMCNT(4);
    PH_MMA(1, 0);
    RA(1, 0); RB(1, 0); stA(u + 2, 0, 0);
    PH_MMA(0, 0);
    RB(1, 1); stA(u + 2, 1, 0);
    PH_MMA(0, 1);
    RA(1, 1); stB(u + 3, 0, 1);
    PH_MMA(1, 1);
    stB(u + 3, 1, 1);
    VMCNT(4);
    PH_MMA(1, 0);
  }
  {
    RA(0, 0); RB(0, 0); stA(31, 0, 1);
    PH_MMA(0, 0);
    RB(0, 1); stA(31, 1, 1);
    PH_MMA(0, 1);
    RA(0, 1);
    PH_MMA(1, 1);
    VMCNT(0);
    PH_MMA(1, 0);
    RA(1, 0); RB(1, 0);
    PH_MMA(0, 0);
    RB(1, 1);
    PH_MMA(0, 1);
    RA(1, 1);
    PH_MMA(1, 1);
    PH_MMA(1, 0);
  }
#undef RA
#undef RB
#undef PH_MMA

#pragma unroll
  for (int qm = 0; qm < 2; ++qm)
#pragma unroll
    for (int mf = 0; mf < 4; ++mf)
#pragma unroll
      for (int qn = 0; qn < 2; ++qn)
#pragma unroll
        for (int nf = 0; nf < 2; ++nf)
#pragma unroll
          for (int r = 0; r < 4; ++r) {
            int row = wm * 128 + qm * 64 + mf * 16 + lg * 4 + r;
            if (row < rows) {
              int col = wn * 64 + qn * 32 + nf * 16 + lc;
              float v = acc[qm][mf][qn][nf][r] * wr_s[row];
              atomicAdd(out + (size_t)toks[row] * 1024 + bn * 256 + col, v);
            }
          }
}

// ---------------------------------------------------------------------------

extern "C" void kernel_launch(void* const* d_in, const int* in_sizes, int n_in,
                              void* d_out, int out_size, void* d_ws, size_t ws_size,
                              hipStream_t stream) {
  (void)in_sizes; (void)n_in; (void)out_size;
  const float* x      = (const float*)d_in[0];
  const float* wroute = (const float*)d_in[1];
  const float* w3     = (const float*)d_in[2];
  const float* wr2h   = (const float*)d_in[3];
  const float* wh2d   = (const float*)d_in[4];
  float* out = (float*)d_out;

  char* ws = (char*)d_ws;
  size_t off = 0;
  auto carve = [&](size_t bytes) -> void* {
    void* p = ws + off; off += (bytes + 255) & ~(size_t)255; return p;
  };
  unsigned short* xh     = (unsigned short*)carve((size_t)8192 * 1024 * 2);
  unsigned short* xl     = (unsigned short*)carve((size_t)8192 * 1024 * 2);
  unsigned short* wrh_t  = (unsigned short*)carve((size_t)8 * 128 * 1024 * 2);
  unsigned short* wrl_t  = (unsigned short*)carve((size_t)8 * 128 * 1024 * 2);
  unsigned short* w3t    = (unsigned short*)carve((size_t)8 * 4096 * 1024 * 2);
  unsigned short* wr2h_t = (unsigned short*)carve((size_t)8 * 4096 * 128 * 2);
  unsigned short* wh2dt  = (unsigned short*)carve((size_t)8 * 1024 * 4096 * 2);
  unsigned short* acts   = (unsigned short*)carve((size_t)8192 * 1024 * 2);
  int*   list01 = (int*)carve(2 * 8192 * 4);
  float* wlist  = (float*)carve(2 * 8192 * 4);
  int*   sel    = (int*)carve(8192 * 2 * 4);
  float* topw   = (float*)carve(8192 * 2 * 4);
  int*   ctr    = (int*)carve(8192);
  int* cnt = ctr; int* fill = ctr + 16; int* offs = ctr + 32;
  float* probsum = (float*)(ctr + 48);
  int4* tilemap = (int4*)(ctr + 64);    // 80 x map256

  size_t avail = ws_size > off ? ws_size - off : 0;
  int tpc = 0;
  const int cands[4] = {160, 80, 40, 20};   // in 128-row units (even)
  for (int i = 0; i < 4; ++i) {
    if ((size_t)cands[i] * 128 * 4096 * 2 <= avail) { tpc = cands[i]; break; }
  }
  if (!tpc) return;
  unsigned short* hbuf = (unsigned short*)(ws + off);

  float* norms_out = out + 8388608;   // [N, E] fp32
  float* bl_out    = out + 8454144;   // scalar

  hipMemsetAsync(out, 0, (size_t)8388608 * 4, stream);
  k_cast_x<<<2048, 256, 0, stream>>>(x, xh, xl);
  k_zero<<<1, 64, 0, stream>>>(cnt, probsum);
  k_transp<<<dim3(16 * 64, 8), 256, 0, stream>>>(w3, w3t, 1024, 4096);
  k_transp<<<dim3(64 * 16, 8), 256, 0, stream>>>(wh2d, wh2dt, 4096, 1024);
  k_transp<<<dim3(2 * 64, 8), 256, 0, stream>>>(wr2h, wr2h_t, 128, 4096);
  k_transp_split<<<dim3(16 * 2, 8), 256, 0, stream>>>(wroute, wrh_t, wrl_t, 1024, 128);
  k_route_gemm<<<dim3(64, 8), 256, 0, stream>>>(xh, xl, wrh_t, wrl_t, acts, norms_out);
  k_router<<<32, 256, 0, stream>>>(norms_out, topw, sel, cnt, probsum);
  k_plan<<<1, 1, 0, stream>>>(cnt, probsum, offs, fill, tilemap, bl_out);
  k_fill<<<32, 256, 0, stream>>>(sel, topw, offs, fill, list01, wlist);

  int nchunk = (160 + tpc - 1) / tpc;
  for (int c = 0; c < nchunk; ++c) {
    int tile_lo = c * tpc;
    int nt = 160 - tile_lo < tpc ? 160 - tile_lo : tpc;
    k_gemm1<<<(nt / 2) * 32, 512, 0, stream>>>(
        xh, acts, w3t, wr2h_t, list01, tilemap, tile_lo / 2, nt / 2, hbuf);
    k_gemm2<<<(nt / 2) * 8, 512, 0, stream>>>(
        hbuf, wh2dt, list01, wlist, tilemap, tile_lo / 2, nt / 2, out);
  }
}